// Round 2
// baseline (211.963 us; speedup 1.0000x reference)
//
#include <hip/hip_runtime.h>
#include <math.h>

typedef __attribute__((ext_vector_type(8)))  short short8v;
typedef __attribute__((ext_vector_type(4)))  short short4v;
typedef __attribute__((ext_vector_type(16))) float f32x16;

#define NB     8
#define SEQ    4096
#define DIM    128
#define KSPLIT 4
#define NSPAN  (SEQ / KSPLIT)   // 1024 k-rows per block
#define BN     64               // k-rows staged in LDS per iter
#define BM     256              // q-rows per block (8 waves x 32)
#define TEMP_INV (1.0f / 11.313708498984761f)
#define EPSF   1e-7f

__device__ __forceinline__ unsigned short f2bf(float x) {
    unsigned u = __float_as_uint(x);
    return (unsigned short)((u + 0x7FFFu + ((u >> 16) & 1u)) >> 16); // RNE
}
__device__ __forceinline__ float bf2f(unsigned short h) {
    return __uint_as_float(((unsigned)h) << 16);
}

// ---------------------------------------------------------------------------
// Phase 1: m_part[b][q][ks] = max over n in ks-range of (q[b,q] . k[b,n]) / T
// bf16 hi/lo split, 3 MFMAs per k-chunk: qh*kh + ql*kh + qh*kl
// ---------------------------------------------------------------------------
__global__ __launch_bounds__(512, 2) void max_scores_kernel(
    const float* __restrict__ qp, const float* __restrict__ kp,
    float* __restrict__ mpart)
{
    __shared__ short khi[BN * DIM];   // 16 KB, XOR-swizzled
    __shared__ short klo[BN * DIM];   // 16 KB

    const int bid   = blockIdx.x;
    const int batch = bid & 7;          // %8 -> XCD-local batch
    const int qt    = (bid >> 3) & 15;
    const int ks    = bid >> 7;

    const int tid   = threadIdx.x;
    const int wv    = tid >> 6;         // 0..7 waves
    const int lane  = tid & 63;
    const int lhalf = lane >> 5;        // k-halfblock selector
    const int l31   = lane & 31;

    const int qrow0 = qt * BM + wv * 32;

    // ---- A fragments: this wave's 32 q-rows, hi/lo, held in registers ----
    short8v ah[8], al[8];
    {
        const float* qrow = qp + ((size_t)(batch * SEQ + qrow0 + l31)) * DIM + lhalf * 8;
        #pragma unroll
        for (int ch = 0; ch < 8; ++ch) {
            float4 x0 = *(const float4*)(qrow + ch * 16);
            float4 x1 = *(const float4*)(qrow + ch * 16 + 4);
            float xs[8] = {x0.x, x0.y, x0.z, x0.w, x1.x, x1.y, x1.z, x1.w};
            short8v h, l;
            #pragma unroll
            for (int j = 0; j < 8; ++j) {
                unsigned short hb = f2bf(xs[j]);
                h[j] = (short)hb;
                l[j] = (short)f2bf(xs[j] - bf2f(hb));
            }
            ah[ch] = h; al[ch] = l;
        }
    }

    f32x16 mx;
    #pragma unroll
    for (int r = 0; r < 16; ++r) mx[r] = -3.0e38f;

    const int srow = tid >> 3;          // 64 rows, 8 threads per row
    const int soct = tid & 7;
    const int skey = (srow & 15) << 3;  // XOR swizzle key (ushort units)

    for (int it = 0; it < NSPAN / BN; ++it) {
        const int n0 = ks * NSPAN + it * BN;
        __syncthreads();
        // stage k-tile: f32 -> bf16 hi/lo into swizzled LDS
        {
            const float* ksrc = kp + ((size_t)(batch * SEQ + n0 + srow)) * DIM + soct * 16;
            #pragma unroll
            for (int i = 0; i < 4; ++i) {
                float4 x = *(const float4*)(ksrc + i * 4);
                int dq  = soct * 16 + i * 4;
                int idx = srow * DIM + (dq ^ skey);
                float xs[4] = {x.x, x.y, x.z, x.w};
                short4v h, l;
                #pragma unroll
                for (int j = 0; j < 4; ++j) {
                    unsigned short hb = f2bf(xs[j]);
                    h[j] = (short)hb;
                    l[j] = (short)f2bf(xs[j] - bf2f(hb));
                }
                *(short4v*)(&khi[idx]) = h;
                *(short4v*)(&klo[idx]) = l;
            }
        }
        __syncthreads();

        #pragma unroll
        for (int ns = 0; ns < 2; ++ns) {
            const int brow = ns * 32 + l31;
            const int bkey = (brow & 15) << 3;
            f32x16 c;
            #pragma unroll
            for (int r = 0; r < 16; ++r) c[r] = 0.f;
            #pragma unroll
            for (int ch = 0; ch < 8; ++ch) {
                const int d0  = ch * 16 + lhalf * 8;
                const int idx = brow * DIM + (d0 ^ bkey);
                short8v bh = *(const short8v*)(&khi[idx]);
                short8v bl = *(const short8v*)(&klo[idx]);
                c = __builtin_amdgcn_mfma_f32_32x32x16_bf16(ah[ch], bh, c, 0, 0, 0);
                c = __builtin_amdgcn_mfma_f32_32x32x16_bf16(al[ch], bh, c, 0, 0, 0);
                c = __builtin_amdgcn_mfma_f32_32x32x16_bf16(ah[ch], bl, c, 0, 0, 0);
            }
            #pragma unroll
            for (int r = 0; r < 16; ++r) mx[r] = fmaxf(mx[r], c[r]);
        }
    }

    // reduce max over columns (32 lanes per half hold 32 k-columns)
    #pragma unroll
    for (int r = 0; r < 16; ++r) {
        float v = mx[r];
        #pragma unroll
        for (int off = 16; off; off >>= 1)
            v = fmaxf(v, __shfl_xor(v, off, 64));
        mx[r] = v;
    }
    if (l31 == 0) {
        #pragma unroll
        for (int r = 0; r < 16; ++r) {
            // verified 32x32 C/D layout: row = (reg&3) + 8*(reg>>2) + 4*(lane>>5)
            int rr = (r & 3) + 8 * (r >> 2) + 4 * lhalf;
            mpart[((size_t)(batch * SEQ + qrow0 + rr)) * KSPLIT + ks] = mx[r] * TEMP_INV;
        }
    }
}

// ---------------------------------------------------------------------------
// Phase 2: per batch — double-exp softmax over q, top-16 threshold, renorm.
// One block (1024 threads) per batch; each thread owns 4 q positions.
// ---------------------------------------------------------------------------
__global__ __launch_bounds__(1024) void softmax_topk_kernel(
    const float* __restrict__ mpart, float* __restrict__ spw,
    float* __restrict__ attn_out, float* __restrict__ loss_out)
{
    const int b   = blockIdx.x;
    const int tid = threadIdx.x;
    __shared__ float red[16];
    __shared__ int   redi[16];
    __shared__ float bcv;
    __shared__ int   bci;

    float m[4];
    #pragma unroll
    for (int j = 0; j < 4; ++j) {
        int qq = tid + j * 1024;
        float4 mp = *(const float4*)(mpart + ((size_t)(b * SEQ + qq)) * KSPLIT);
        m[j] = fmaxf(fmaxf(mp.x, mp.y), fmaxf(mp.z, mp.w));
    }

    // block max of m
    float lm = fmaxf(fmaxf(m[0], m[1]), fmaxf(m[2], m[3]));
    for (int off = 32; off; off >>= 1) lm = fmaxf(lm, __shfl_down(lm, off, 64));
    if ((tid & 63) == 0) red[tid >> 6] = lm;
    __syncthreads();
    if (tid == 0) { float v = red[0]; for (int i = 1; i < 16; ++i) v = fmaxf(v, red[i]); bcv = v; }
    __syncthreads();
    const float S = expf(bcv);   // max over q of s = exp(m)
    __syncthreads();

    float e[4];
    float ls = 0.f;
    #pragma unroll
    for (int j = 0; j < 4; ++j) { e[j] = expf(expf(m[j]) - S); ls += e[j]; }
    for (int off = 32; off; off >>= 1) ls += __shfl_down(ls, off, 64);
    if ((tid & 63) == 0) red[tid >> 6] = ls;
    __syncthreads();
    if (tid == 0) { float v = 0.f; for (int i = 0; i < 16; ++i) v += red[i]; bcv = v; }
    __syncthreads();
    const float Z = bcv;
    __syncthreads();

    float attn[4], a[4];
    #pragma unroll
    for (int j = 0; j < 4; ++j) { attn[j] = e[j] / Z; a[j] = attn[j]; }

    // 16 passes of block-argmax with removal -> 16th largest attn value
    float v16 = 0.f;
    for (int pass = 0; pass < 16; ++pass) {
        float v = -1.f; int ix = -1;
        #pragma unroll
        for (int j = 0; j < 4; ++j) { if (a[j] > v) { v = a[j]; ix = tid + j * 1024; } }
        for (int off = 32; off; off >>= 1) {
            float ov = __shfl_down(v, off, 64);
            int   oi = __shfl_down(ix, off, 64);
            if (ov > v || (ov == v && oi < ix)) { v = ov; ix = oi; }
        }
        if ((tid & 63) == 0) { red[tid >> 6] = v; redi[tid >> 6] = ix; }
        __syncthreads();
        if (tid == 0) {
            float bv = red[0]; int bi = redi[0];
            for (int i = 1; i < 16; ++i) {
                if (red[i] > bv || (red[i] == bv && redi[i] < bi)) { bv = red[i]; bi = redi[i]; }
            }
            bcv = bv; bci = bi;
        }
        __syncthreads();
        v16 = bcv;
        int win = bci;
        #pragma unroll
        for (int j = 0; j < 4; ++j) { if (tid + j * 1024 == win) a[j] = -2.f; }
        __syncthreads();
    }
    const float delta = v16 + EPSF;

    float w[4]; float lw = 0.f;
    #pragma unroll
    for (int j = 0; j < 4; ++j) { w[j] = fmaxf(attn[j] - delta, 0.f); lw += w[j]; }
    for (int off = 32; off; off >>= 1) lw += __shfl_down(lw, off, 64);
    if ((tid & 63) == 0) red[tid >> 6] = lw;
    __syncthreads();
    if (tid == 0) { float v = 0.f; for (int i = 0; i < 16; ++i) v += red[i]; bcv = v; }
    __syncthreads();
    const float rW = 1.f / (bcv + EPSF);

    #pragma unroll
    for (int j = 0; j < 4; ++j) {
        int qq = tid + j * 1024;
        float spv = w[j] * rW;
        spw[b * SEQ + qq]      = spv;   // scratch for phase 3
        attn_out[b * SEQ + qq] = spv;   // output 1 (attn3)
    }
    if (b == 0 && tid == 0) loss_out[0] = 0.f;  // output 2 (extra_loss)
}

// ---------------------------------------------------------------------------
// Phase 3: out[b,q,d] = sp[b,q] * v[b,0,d]  (float4 per thread)
// ---------------------------------------------------------------------------
__global__ void broadcast_out_kernel(const float* __restrict__ spw,
                                     const float* __restrict__ vp,
                                     float* __restrict__ outp)
{
    int gid = blockIdx.x * 256 + threadIdx.x;  // 0 .. NB*SEQ*DIM/4 - 1
    int row = gid >> 5;                        // b*SEQ + q  (32 float4 per row)
    int c4  = gid & 31;
    float  s  = spw[row];
    float4 vv = *(const float4*)(vp + (row >> 12) * DIM + c4 * 4);
    float4 o; o.x = s * vv.x; o.y = s * vv.y; o.z = s * vv.z; o.w = s * vv.w;
    *(float4*)(outp + (size_t)gid * 4) = o;
}

// ---------------------------------------------------------------------------
extern "C" void kernel_launch(void* const* d_in, const int* in_sizes, int n_in,
                              void* d_out, int out_size, void* d_ws, size_t ws_size,
                              hipStream_t stream)
{
    (void)in_sizes; (void)n_in; (void)out_size; (void)ws_size;
    const float* q = (const float*)d_in[0];
    const float* k = (const float*)d_in[1];
    const float* v = (const float*)d_in[2];
    float* out   = (float*)d_out;
    float* mpart = (float*)d_ws;                 // [NB][SEQ][KSPLIT] f32
    float* spw   = mpart + (size_t)NB * SEQ * KSPLIT;  // [NB][SEQ] f32

    hipLaunchKernelGGL(max_scores_kernel, dim3(NB * (SEQ / BM) * KSPLIT), dim3(512), 0, stream,
                       q, k, mpart);
    hipLaunchKernelGGL(softmax_topk_kernel, dim3(NB), dim3(1024), 0, stream,
                       mpart, spw, out + (size_t)NB * SEQ * DIM,
                       out + (size_t)NB * SEQ * DIM + (size_t)NB * SEQ);
    hipLaunchKernelGGL(broadcast_out_kernel, dim3((NB * SEQ * DIM / 4) / 256), dim3(256), 0, stream,
                       spw, v, out);
}

// Round 4
// 195.349 us; speedup vs baseline: 1.0850x; 1.0850x over previous
//
#include <hip/hip_runtime.h>
#include <math.h>

typedef __attribute__((ext_vector_type(8)))  short short8v;
typedef __attribute__((ext_vector_type(4)))  short short4v;
typedef __attribute__((ext_vector_type(16))) float f32x16;

#define NB     8
#define SEQ    4096
#define DIM    128
#define KSPLIT 4
#define NSPAN  (SEQ / KSPLIT)   // 1024 k-rows per block
#define BN     64               // k-rows per LDS tile
#define BM     256              // q-rows per block (8 waves x 32)
#define TEMP_INV (1.0f / 11.313708498984761f)
#define EPSF   1e-7f
#define NEGINF -3.0e38f

__device__ __forceinline__ unsigned short f2bf(float x) {
    unsigned u = __float_as_uint(x);
    return (unsigned short)((u + 0x7FFFu + ((u >> 16) & 1u)) >> 16); // RNE
}
__device__ __forceinline__ float bf2f(unsigned short h) {
    return __uint_as_float(((unsigned)h) << 16);
}

// async global->LDS, 16B per lane; LDS dest is wave-uniform base + lane*16
#define GL_LDS16(gsrc, ldst)                                                              \
    __builtin_amdgcn_global_load_lds((const __attribute__((address_space(1))) void*)(gsrc), \
                                     (__attribute__((address_space(3))) void*)(ldst), 16, 0, 0)

// ---------------------------------------------------------------------------
// Pre-pass: K f32 -> bf16 hi/lo, row layout [hi 128 | lo 128] ushorts (512B),
// hi/lo elements stored at position d ^ ((row&15)<<3)  (pre-swizzled global).
// ---------------------------------------------------------------------------
__global__ __launch_bounds__(256) void split_k_kernel(
    const float* __restrict__ kp, unsigned short* __restrict__ ks)
{
    int t    = blockIdx.x * 256 + threadIdx.x;   // 0 .. NB*SEQ*8-1
    int row  = t >> 3;
    int soct = t & 7;
    const float* src = kp + (size_t)row * DIM + soct * 16;
    unsigned short* dst = ks + (size_t)row * 256;
    int key = (row & 15) << 3;
    #pragma unroll
    for (int i = 0; i < 4; ++i) {
        float4 x = *(const float4*)(src + i * 4);
        int p = (soct * 16 + i * 4) ^ key;       // XOR flips bits>=3 only; 4-chunk stays contiguous
        float xs[4] = {x.x, x.y, x.z, x.w};
        short4v h, l;
        #pragma unroll
        for (int j = 0; j < 4; ++j) {
            unsigned short hb = f2bf(xs[j]);
            h[j] = (short)hb;
            l[j] = (short)f2bf(xs[j] - bf2f(hb));
        }
        *(short4v*)(dst + p)       = h;
        *(short4v*)(dst + 128 + p) = l;
    }
}

// ---------------------------------------------------------------------------
// Phase 1 (fast path): m_part over pre-split K via async global_load_lds,
// double-buffered LDS, 3x bf16 MFMA (qh*kh + ql*kh + qh*kl).
// ---------------------------------------------------------------------------
__global__ __launch_bounds__(512, 4) void max_scores2_kernel(
    const float* __restrict__ qp, const unsigned short* __restrict__ ksp,
    float* __restrict__ mpart)
{
    __shared__ __align__(16) unsigned short kbuf[2][BN * 256]; // 2 x 32KB

    const int bid   = blockIdx.x;
    const int batch = bid & 7;          // %8 -> XCD-local batch
    const int qt    = (bid >> 3) & 15;
    const int ks    = bid >> 7;

    const int tid   = threadIdx.x;
    const int wv    = tid >> 6;
    const int lane  = tid & 63;
    const int lhalf = lane >> 5;
    const int l31   = lane & 31;
    const int qrow0 = qt * BM + wv * 32;

    const char* ktile0 = (const char*)(ksp + ((size_t)(batch * SEQ + ks * NSPAN)) * 256);
    const int   woff   = wv * 4096;     // per-wave byte slice of the 32KB tile

    // stage tile 0 (async; overlaps A-frag build below)
    #pragma unroll
    for (int r = 0; r < 4; ++r) {
        int off = woff + r * 1024;
        GL_LDS16(ktile0 + off + lane * 16, (char*)&kbuf[0][0] + off);
    }

    // ---- A fragments: this wave's 32 q-rows, hi/lo, in registers ----
    short8v ah[8], al[8];
    {
        const float* qrow = qp + ((size_t)(batch * SEQ + qrow0 + l31)) * DIM + lhalf * 8;
        #pragma unroll
        for (int ch = 0; ch < 8; ++ch) {
            float4 x0 = *(const float4*)(qrow + ch * 16);
            float4 x1 = *(const float4*)(qrow + ch * 16 + 4);
            float xs[8] = {x0.x, x0.y, x0.z, x0.w, x1.x, x1.y, x1.z, x1.w};
            short8v h, l;
            #pragma unroll
            for (int j = 0; j < 8; ++j) {
                unsigned short hb = f2bf(xs[j]);
                h[j] = (short)hb;
                l[j] = (short)f2bf(xs[j] - bf2f(hb));
            }
            ah[ch] = h; al[ch] = l;
        }
    }

    f32x16 mx;
    #pragma unroll
    for (int r = 0; r < 16; ++r) mx[r] = NEGINF;

    __syncthreads();   // drains vmcnt -> tile 0 resident

    int cur = 0;
    for (int it = 0; it < NSPAN / BN; ++it) {
        if (it < NSPAN / BN - 1) {       // prefetch next tile into other buffer
            const char* src = ktile0 + (size_t)(it + 1) * (BN * 512);
            #pragma unroll
            for (int r = 0; r < 4; ++r) {
                int off = woff + r * 1024;
                GL_LDS16(src + off + lane * 16, (char*)&kbuf[cur ^ 1][0] + off);
            }
        }
        #pragma unroll
        for (int ns = 0; ns < 2; ++ns) {
            const int  brow = ns * 32 + l31;
            const int  bkey = (l31 & 15) << 3;
            const char* base = (const char*)&kbuf[cur][0] + brow * 512;
            f32x16 c;
            #pragma unroll
            for (int r = 0; r < 16; ++r) c[r] = 0.f;
            #pragma unroll
            for (int ch = 0; ch < 8; ++ch) {
                const int d0   = ch * 16 + lhalf * 8;
                const int boff = 2 * (d0 ^ bkey);
                short8v bh = *(const short8v*)(base + boff);
                short8v bl = *(const short8v*)(base + 256 + boff);
                c = __builtin_amdgcn_mfma_f32_32x32x16_bf16(ah[ch], bh, c, 0, 0, 0);
                c = __builtin_amdgcn_mfma_f32_32x32x16_bf16(al[ch], bh, c, 0, 0, 0);
                c = __builtin_amdgcn_mfma_f32_32x32x16_bf16(ah[ch], bl, c, 0, 0, 0);
            }
            #pragma unroll
            for (int r = 0; r < 16; ++r) mx[r] = fmaxf(mx[r], c[r]);
        }
        __syncthreads();   // drains vmcnt (prefetch landed) + all waves done reading cur
        cur ^= 1;
    }

    #pragma unroll
    for (int r = 0; r < 16; ++r) {
        float v = mx[r];
        #pragma unroll
        for (int off = 16; off; off >>= 1)
            v = fmaxf(v, __shfl_xor(v, off, 64));
        mx[r] = v;
    }
    if (l31 == 0) {
        #pragma unroll
        for (int r = 0; r < 16; ++r) {
            int rr = (r & 3) + 8 * (r >> 2) + 4 * lhalf;  // verified 32x32 C/D row map
            mpart[((size_t)(batch * SEQ + qrow0 + rr)) * KSPLIT + ks] = mx[r] * TEMP_INV;
        }
    }
}

// ---------------------------------------------------------------------------
// Phase 1 (fallback if ws too small): round-2 proven kernel, unchanged.
// ---------------------------------------------------------------------------
__global__ __launch_bounds__(512, 2) void max_scores_kernel(
    const float* __restrict__ qp, const float* __restrict__ kp,
    float* __restrict__ mpart)
{
    __shared__ short khi[BN * DIM];
    __shared__ short klo[BN * DIM];

    const int bid   = blockIdx.x;
    const int batch = bid & 7;
    const int qt    = (bid >> 3) & 15;
    const int ks    = bid >> 7;
    const int tid   = threadIdx.x;
    const int wv    = tid >> 6;
    const int lane  = tid & 63;
    const int lhalf = lane >> 5;
    const int l31   = lane & 31;
    const int qrow0 = qt * BM + wv * 32;

    short8v ah[8], al[8];
    {
        const float* qrow = qp + ((size_t)(batch * SEQ + qrow0 + l31)) * DIM + lhalf * 8;
        #pragma unroll
        for (int ch = 0; ch < 8; ++ch) {
            float4 x0 = *(const float4*)(qrow + ch * 16);
            float4 x1 = *(const float4*)(qrow + ch * 16 + 4);
            float xs[8] = {x0.x, x0.y, x0.z, x0.w, x1.x, x1.y, x1.z, x1.w};
            short8v h, l;
            #pragma unroll
            for (int j = 0; j < 8; ++j) {
                unsigned short hb = f2bf(xs[j]);
                h[j] = (short)hb;
                l[j] = (short)f2bf(xs[j] - bf2f(hb));
            }
            ah[ch] = h; al[ch] = l;
        }
    }

    f32x16 mx;
    #pragma unroll
    for (int r = 0; r < 16; ++r) mx[r] = NEGINF;

    const int srow = tid >> 3;
    const int soct = tid & 7;
    const int skey = (srow & 15) << 3;

    for (int it = 0; it < NSPAN / BN; ++it) {
        const int n0 = ks * NSPAN + it * BN;
        __syncthreads();
        {
            const float* ksrc = kp + ((size_t)(batch * SEQ + n0 + srow)) * DIM + soct * 16;
            #pragma unroll
            for (int i = 0; i < 4; ++i) {
                float4 x = *(const float4*)(ksrc + i * 4);
                int dq  = soct * 16 + i * 4;
                int idx = srow * DIM + (dq ^ skey);
                float xs[4] = {x.x, x.y, x.z, x.w};
                short4v h, l;
                #pragma unroll
                for (int j = 0; j < 4; ++j) {
                    unsigned short hb = f2bf(xs[j]);
                    h[j] = (short)hb;
                    l[j] = (short)f2bf(xs[j] - bf2f(hb));
                }
                *(short4v*)(&khi[idx]) = h;
                *(short4v*)(&klo[idx]) = l;
            }
        }
        __syncthreads();

        #pragma unroll
        for (int ns = 0; ns < 2; ++ns) {
            const int brow = ns * 32 + l31;
            const int bkey = (brow & 15) << 3;
            f32x16 c;
            #pragma unroll
            for (int r = 0; r < 16; ++r) c[r] = 0.f;
            #pragma unroll
            for (int ch = 0; ch < 8; ++ch) {
                const int d0  = ch * 16 + lhalf * 8;
                const int idx = brow * DIM + (d0 ^ bkey);
                short8v bh = *(const short8v*)(&khi[idx]);
                short8v bl = *(const short8v*)(&klo[idx]);
                c = __builtin_amdgcn_mfma_f32_32x32x16_bf16(ah[ch], bh, c, 0, 0, 0);
                c = __builtin_amdgcn_mfma_f32_32x32x16_bf16(al[ch], bh, c, 0, 0, 0);
                c = __builtin_amdgcn_mfma_f32_32x32x16_bf16(ah[ch], bl, c, 0, 0, 0);
            }
            #pragma unroll
            for (int r = 0; r < 16; ++r) mx[r] = fmaxf(mx[r], c[r]);
        }
    }

    #pragma unroll
    for (int r = 0; r < 16; ++r) {
        float v = mx[r];
        #pragma unroll
        for (int off = 16; off; off >>= 1)
            v = fmaxf(v, __shfl_xor(v, off, 64));
        mx[r] = v;
    }
    if (l31 == 0) {
        #pragma unroll
        for (int r = 0; r < 16; ++r) {
            int rr = (r & 3) + 8 * (r >> 2) + 4 * lhalf;
            mpart[((size_t)(batch * SEQ + qrow0 + rr)) * KSPLIT + ks] = mx[r] * TEMP_INV;
        }
    }
}

// ---------------------------------------------------------------------------
// Phase 2: softmax over q + top-16 threshold + renorm.
// top-16(attn) == top-16(m) since attn = exp(exp(m)-S)/Z is monotone in m.
// 2-level selection (per-wave 16-pass, wave0 merge). 4 block barriers total.
// ---------------------------------------------------------------------------
__global__ __launch_bounds__(1024) void softmax_topk2_kernel(
    const float* __restrict__ mpart, float* __restrict__ attn_out,
    float* __restrict__ loss_out)
{
    const int b    = blockIdx.x;
    const int tid  = threadIdx.x;
    const int wv   = tid >> 6;
    const int lane = tid & 63;
    __shared__ float cand[256];
    __shared__ float smZ[16], smW[16];
    __shared__ float bc[2];

    float m[4];
    #pragma unroll
    for (int j = 0; j < 4; ++j) {
        int qq = tid + j * 1024;
        float4 mp = *(const float4*)(mpart + ((size_t)(b * SEQ + qq)) * KSPLIT);
        m[j] = fmaxf(fmaxf(mp.x, mp.y), fmaxf(mp.z, mp.w));
    }

    // per-wave top-16 of its 256 values (multiset semantics: remove 1/pass)
    {
        float a0 = m[0], a1 = m[1], a2 = m[2], a3 = m[3];
        for (int pass = 0; pass < 16; ++pass) {
            float v = fmaxf(fmaxf(a0, a1), fmaxf(a2, a3));
            #pragma unroll
            for (int off = 32; off; off >>= 1) v = fmaxf(v, __shfl_xor(v, off, 64));
            bool has = (a0 == v) || (a1 == v) || (a2 == v) || (a3 == v);
            unsigned long long msk = __ballot(has);
            int leader = __ffsll(msk) - 1;
            if (lane == leader) {
                if (a0 == v) a0 = NEGINF;
                else if (a1 == v) a1 = NEGINF;
                else if (a2 == v) a2 = NEGINF;
                else a3 = NEGINF;
            }
            if (lane == pass) cand[wv * 16 + pass] = v;
        }
    }
    __syncthreads();

    // wave 0 merges 16x16 candidates -> m_max (pass 0) and m16 (pass 15)
    if (wv == 0) {
        float a0 = cand[lane * 4 + 0], a1 = cand[lane * 4 + 1];
        float a2 = cand[lane * 4 + 2], a3 = cand[lane * 4 + 3];
        float first = 0.f, last = 0.f;
        for (int pass = 0; pass < 16; ++pass) {
            float v = fmaxf(fmaxf(a0, a1), fmaxf(a2, a3));
            #pragma unroll
            for (int off = 32; off; off >>= 1) v = fmaxf(v, __shfl_xor(v, off, 64));
            bool has = (a0 == v) || (a1 == v) || (a2 == v) || (a3 == v);
            unsigned long long msk = __ballot(has);
            int leader = __ffsll(msk) - 1;
            if (lane == leader) {
                if (a0 == v) a0 = NEGINF;
                else if (a1 == v) a1 = NEGINF;
                else if (a2 == v) a2 = NEGINF;
                else a3 = NEGINF;
            }
            if (pass == 0) first = v;
            last = v;
        }
        if (lane == 0) { bc[0] = first; bc[1] = last; }
    }
    __syncthreads();

    const float S   = expf(bc[0]);   // max over q of s = exp(m)
    const float m16 = bc[1];

    float e[4]; float ls = 0.f;
    #pragma unroll
    for (int j = 0; j < 4; ++j) { e[j] = expf(expf(m[j]) - S); ls += e[j]; }
    #pragma unroll
    for (int off = 32; off; off >>= 1) ls += __shfl_xor(ls, off, 64);
    if (lane == 0) smZ[wv] = ls;
    __syncthreads();
    float Z = 0.f;
    #pragma unroll
    for (int i = 0; i < 16; ++i) Z += smZ[i];   // broadcast reads

    const float a16   = expf(expf(m16) - S) / Z;  // same ops as owner's attn
    const float delta = a16 + EPSF;

    float w0[4]; float lw = 0.f;
    #pragma unroll
    for (int j = 0; j < 4; ++j) { w0[j] = fmaxf(e[j] / Z - delta, 0.f); lw += w0[j]; }
    #pragma unroll
    for (int off = 32; off; off >>= 1) lw += __shfl_xor(lw, off, 64);
    if (lane == 0) smW[wv] = lw;
    __syncthreads();
    float W = 0.f;
    #pragma unroll
    for (int i = 0; i < 16; ++i) W += smW[i];
    const float rW = 1.f / (W + EPSF);

    #pragma unroll
    for (int j = 0; j < 4; ++j)
        attn_out[b * SEQ + tid + j * 1024] = w0[j] * rW;
    if (b == 0 && tid == 0) loss_out[0] = 0.f;
}

// ---------------------------------------------------------------------------
// Phase 3: out[b,q,d] = sp[b,q] * v[b,0,d]
// ---------------------------------------------------------------------------
__global__ void broadcast_out_kernel(const float* __restrict__ sp,
                                     const float* __restrict__ vp,
                                     float* __restrict__ outp)
{
    int gid = blockIdx.x * 256 + threadIdx.x;
    int row = gid >> 5;
    int c4  = gid & 31;
    float  s  = sp[row];
    float4 vv = *(const float4*)(vp + (row >> 12) * DIM + c4 * 4);
    float4 o; o.x = s * vv.x; o.y = s * vv.y; o.z = s * vv.z; o.w = s * vv.w;
    *(float4*)(outp + (size_t)gid * 4) = o;
}

// ---------------------------------------------------------------------------
extern "C" void kernel_launch(void* const* d_in, const int* in_sizes, int n_in,
                              void* d_out, int out_size, void* d_ws, size_t ws_size,
                              hipStream_t stream)
{
    (void)in_sizes; (void)n_in; (void)out_size;
    const float* q = (const float*)d_in[0];
    const float* k = (const float*)d_in[1];
    const float* v = (const float*)d_in[2];
    float* out  = (float*)d_out;
    float* attn = out + (size_t)NB * SEQ * DIM;
    float* loss = attn + (size_t)NB * SEQ;

    const size_t KSPLIT_BYTES = (size_t)NB * SEQ * 256 * 2;       // 16 MB pre-split K
    const size_t MPART_BYTES  = (size_t)NB * SEQ * KSPLIT * 4;    // 512 KB

    float* mpart;
    if (ws_size >= KSPLIT_BYTES + MPART_BYTES) {
        unsigned short* ksplit = (unsigned short*)d_ws;
        mpart = (float*)((char*)d_ws + KSPLIT_BYTES);
        hipLaunchKernelGGL(split_k_kernel, dim3(NB * SEQ * 8 / 256), dim3(256), 0, stream, k, ksplit);
        hipLaunchKernelGGL(max_scores2_kernel, dim3(NB * (SEQ / BM) * KSPLIT), dim3(512), 0, stream,
                           q, ksplit, mpart);
    } else {
        mpart = (float*)d_ws;
        hipLaunchKernelGGL(max_scores_kernel, dim3(NB * (SEQ / BM) * KSPLIT), dim3(512), 0, stream,
                           q, k, mpart);
    }
    hipLaunchKernelGGL(softmax_topk2_kernel, dim3(NB), dim3(1024), 0, stream, mpart, attn, loss);
    hipLaunchKernelGGL(broadcast_out_kernel, dim3((NB * SEQ * DIM / 4) / 256), dim3(256), 0, stream,
                       attn, v, out);
}

// Round 7
// 166.273 us; speedup vs baseline: 1.2748x; 1.1749x over previous
//
#include <hip/hip_runtime.h>
#include <math.h>

typedef __attribute__((ext_vector_type(8)))  short short8v;
typedef __attribute__((ext_vector_type(4)))  short short4v;
typedef __attribute__((ext_vector_type(16))) float f32x16;

#define NB     8
#define SEQ    4096
#define DIM    128
#define KSPLIT 4
#define NSPAN  (SEQ / KSPLIT)   // 1024 k-rows per region
#define BN     64               // k-rows per LDS tile
#define BM     256              // q-rows per block (8 waves x 32)
#define TEMP_INV (1.0f / 11.313708498984761f)
#define EPSF   1e-7f
#define NEGINF -3.0e38f

__device__ __forceinline__ unsigned short f2bf(float x) {
    unsigned u = __float_as_uint(x);
    return (unsigned short)((u + 0x7FFFu + ((u >> 16) & 1u)) >> 16); // RNE
}
__device__ __forceinline__ float bf2f(unsigned short h) {
    return __uint_as_float(((unsigned)h) << 16);
}
__device__ __forceinline__ unsigned umaxu(unsigned a, unsigned b) { return a > b ? a : b; }

// async global->LDS, 16B per lane; LDS dest is wave-uniform base + lane*16
#define GL_LDS16(gsrc, ldst)                                                              \
    __builtin_amdgcn_global_load_lds((const __attribute__((address_space(1))) void*)(gsrc), \
                                     (__attribute__((address_space(3))) void*)(ldst), 16, 0, 0)

// ---------------------------------------------------------------------------
// Pre-pass: K f32 -> bf16 HI only, row = 128 ushort (256B), element d stored
// at position d ^ ((row&15)<<3)  (pre-swizzled global, m173 pattern).
// ---------------------------------------------------------------------------
__global__ __launch_bounds__(256) void split_khi_kernel(
    const float* __restrict__ kp, unsigned short* __restrict__ kh)
{
    int t    = blockIdx.x * 256 + threadIdx.x;   // 0 .. NB*SEQ*4-1
    int row  = t >> 2;
    int part = t & 3;
    const float* src = kp + (size_t)row * DIM + part * 32;
    unsigned short* dst = kh + (size_t)row * DIM;
    int key = (row & 15) << 3;
    #pragma unroll
    for (int c = 0; c < 4; ++c) {                // 4 chunks of 8 elems
        int d = part * 32 + c * 8;               // (d^key) preserves +0..7 (key flips bits>=3)
        float4 x0 = *(const float4*)(src + c * 8);
        float4 x1 = *(const float4*)(src + c * 8 + 4);
        short8v h;
        h[0] = (short)f2bf(x0.x); h[1] = (short)f2bf(x0.y);
        h[2] = (short)f2bf(x0.z); h[3] = (short)f2bf(x0.w);
        h[4] = (short)f2bf(x1.x); h[5] = (short)f2bf(x1.y);
        h[6] = (short)f2bf(x1.z); h[7] = (short)f2bf(x1.w);
        *(short8v*)(dst + (d ^ key)) = h;
    }
}

// ---------------------------------------------------------------------------
// Phase 1: hi-only qh.kh via MFMA; per (q-row, ks-region) select top-2
// candidate k indices (packed monotone u32 keys), for exact rescoring.
// ---------------------------------------------------------------------------
__global__ __launch_bounds__(512, 4) void max_hi_kernel(
    const float* __restrict__ qp, const unsigned short* __restrict__ khp,
    unsigned int* __restrict__ cand)
{
    __shared__ __align__(16) unsigned short kbuf[2][BN * DIM]; // 2 x 16KB

    const int bid   = blockIdx.x;
    const int batch = bid & 7;          // %8 -> XCD-local batch
    const int qt    = (bid >> 3) & 15;
    const int ks    = bid >> 7;

    const int tid   = threadIdx.x;
    const int wv    = tid >> 6;
    const int lane  = tid & 63;
    const int lhalf = lane >> 5;
    const int l31   = lane & 31;
    const int qrow0 = qt * BM + wv * 32;

    const char* ktile0 = (const char*)(khp + ((size_t)(batch * SEQ + ks * NSPAN)) * DIM);
    const int   woff   = wv * 2048;     // per-wave byte slice of the 16KB tile

    // stage tile 0 (async; overlaps A-frag build)
    #pragma unroll
    for (int r = 0; r < 2; ++r) {
        int off = woff + r * 1024;
        GL_LDS16(ktile0 + off + lane * 16, (char*)&kbuf[0][0] + off);
    }

    // ---- A fragments: hi only ----
    short8v ah[8];
    {
        const float* qrow = qp + ((size_t)(batch * SEQ + qrow0 + l31)) * DIM + lhalf * 8;
        #pragma unroll
        for (int ch = 0; ch < 8; ++ch) {
            float4 x0 = *(const float4*)(qrow + ch * 16);
            float4 x1 = *(const float4*)(qrow + ch * 16 + 4);
            short8v h;
            h[0] = (short)f2bf(x0.x); h[1] = (short)f2bf(x0.y);
            h[2] = (short)f2bf(x0.z); h[3] = (short)f2bf(x0.w);
            h[4] = (short)f2bf(x1.x); h[5] = (short)f2bf(x1.y);
            h[6] = (short)f2bf(x1.z); h[7] = (short)f2bf(x1.w);
            ah[ch] = h;
        }
    }

    // packed running max per (acc-reg, ns): key = bits(dot+128) & ~15 | iter
    unsigned pk0[16], pk1[16];
    #pragma unroll
    for (int r = 0; r < 16; ++r) { pk0[r] = 0u; pk1[r] = 0u; }

    __syncthreads();   // tile 0 resident

    int cur = 0;
    for (int it = 0; it < NSPAN / BN; ++it) {
        if (it < NSPAN / BN - 1) {       // prefetch next tile
            const char* src = ktile0 + (size_t)(it + 1) * (BN * 256);
            #pragma unroll
            for (int r = 0; r < 2; ++r) {
                int off = woff + r * 1024;
                GL_LDS16(src + off + lane * 16, (char*)&kbuf[cur ^ 1][0] + off);
            }
        }
        __builtin_amdgcn_s_setprio(1);
        const unsigned itb = (unsigned)it;
        #pragma unroll
        for (int ns = 0; ns < 2; ++ns) {
            const int  brow = ns * 32 + l31;
            const int  bkey = (l31 & 15) << 3;
            const char* base = (const char*)&kbuf[cur][0] + brow * 256;
            f32x16 c;
            #pragma unroll
            for (int r = 0; r < 16; ++r) c[r] = 0.f;
            #pragma unroll
            for (int ch = 0; ch < 8; ++ch) {
                const int boff = 2 * ((ch * 16 + lhalf * 8) ^ bkey);
                short8v bh = *(const short8v*)(base + boff);
                c = __builtin_amdgcn_mfma_f32_32x32x16_bf16(ah[ch], bh, c, 0, 0, 0);
            }
            #pragma unroll
            for (int r = 0; r < 16; ++r) {
                unsigned pv = (__float_as_uint(c[r] + 128.f) & 0xFFFFFFF0u) | itb;
                if (ns == 0) pk0[r] = umaxu(pk0[r], pv);
                else         pk1[r] = umaxu(pk1[r], pv);
            }
        }
        __builtin_amdgcn_s_setprio(0);
        __syncthreads();
        cur ^= 1;
    }

    // epilogue: per row, top-2 over 64 (lane,ns) class winners, with indices
    #pragma unroll
    for (int r = 0; r < 16; ++r) {
        unsigned k0 = pk0[r], k1v = pk1[r];
        unsigned i0  = ((k0 & 15u) << 6)  | l31;        // it*64 + ns*32 + l31
        unsigned i1v = ((k1v & 15u) << 6) | 32u | l31;
        unsigned t1, t1i, t2, t2i;
        if (k0 >= k1v) { t1 = k0;  t1i = i0;  t2 = k1v; t2i = i1v; }
        else           { t1 = k1v; t1i = i1v; t2 = k0;  t2i = i0;  }
        #pragma unroll
        for (int off = 1; off <= 16; off <<= 1) {       // within 32-lane half
            unsigned o1  = (unsigned)__shfl_xor((int)t1,  off, 64);
            unsigned o1i = (unsigned)__shfl_xor((int)t1i, off, 64);
            unsigned o2  = (unsigned)__shfl_xor((int)t2,  off, 64);
            unsigned o2i = (unsigned)__shfl_xor((int)t2i, off, 64);
            bool og = o1 > t1;
            unsigned n1  = og ? o1  : t1;
            unsigned n1i = og ? o1i : t1i;
            unsigned a2  = og ? t1  : o1;   // loser of top compare
            unsigned a2i = og ? t1i : o1i;
            unsigned b2  = og ? o2  : t2;   // winner side's 2nd
            unsigned b2i = og ? o2i : t2i;
            bool ag = a2 > b2;
            t1 = n1; t1i = n1i;
            t2 = ag ? a2 : b2; t2i = ag ? a2i : b2i;
        }
        if (l31 == 0) {
            int rr = (r & 3) + 8 * (r >> 2) + 4 * lhalf;  // verified 32x32 C/D row map
            cand[((size_t)(batch * SEQ + qrow0 + rr)) * KSPLIT + ks] =
                (t1i & 0xFFFFu) | (t2i << 16);
        }
    }
}

// ---------------------------------------------------------------------------
// Phase 1b: exact f32 rescore of the 8 candidates per q-row -> mq[b][q]
// One wave per q-row; 8 lane-groups of 8, one candidate each.
// ---------------------------------------------------------------------------
__global__ __launch_bounds__(256) void rescore_kernel(
    const float* __restrict__ qp, const float* __restrict__ kp,
    const unsigned int* __restrict__ cand, float* __restrict__ mq)
{
    const int row  = blockIdx.x * 4 + (threadIdx.x >> 6);   // b*SEQ + q
    const int lane = threadIdx.x & 63;
    const int b    = row >> 12;
    const int g    = lane >> 3;      // candidate group 0..7
    const int t8   = lane & 7;
    const int ks   = g >> 1;
    unsigned cc  = cand[(size_t)row * KSPLIT + ks];
    unsigned idx = (g & 1) ? (cc >> 16) : (cc & 0xFFFFu);   // 0..1023
    const float* qrow = qp + (size_t)row * DIM + t8 * 16;
    const float* krow = kp + ((size_t)(b * SEQ + ks * NSPAN + (int)idx)) * DIM + t8 * 16;
    float s = 0.f;
    #pragma unroll
    for (int i = 0; i < 4; ++i) {
        float4 a  = *(const float4*)(qrow + i * 4);
        float4 kk = *(const float4*)(krow + i * 4);
        s += a.x * kk.x + a.y * kk.y + a.z * kk.z + a.w * kk.w;
    }
    #pragma unroll
    for (int off = 1; off <= 4; off <<= 1) s += __shfl_xor(s, off, 64);      // sum within group
    #pragma unroll
    for (int off = 8; off <= 32; off <<= 1) s = fmaxf(s, __shfl_xor(s, off, 64)); // max across groups
    if (lane == 0) mq[row] = s * TEMP_INV;
}

// ---------------------------------------------------------------------------
// Fallback phase 1 (proven round-2 kernel): 3-product exact-ish max -> mpart
// ---------------------------------------------------------------------------
__global__ __launch_bounds__(512, 2) void max_scores_kernel(
    const float* __restrict__ qp, const float* __restrict__ kp,
    float* __restrict__ mpart)
{
    __shared__ short khi[BN * DIM];
    __shared__ short klo[BN * DIM];

    const int bid   = blockIdx.x;
    const int batch = bid & 7;
    const int qt    = (bid >> 3) & 15;
    const int ks    = bid >> 7;
    const int tid   = threadIdx.x;
    const int wv    = tid >> 6;
    const int lane  = tid & 63;
    const int lhalf = lane >> 5;
    const int l31   = lane & 31;
    const int qrow0 = qt * BM + wv * 32;

    short8v ah[8], al[8];
    {
        const float* qrow = qp + ((size_t)(batch * SEQ + qrow0 + l31)) * DIM + lhalf * 8;
        #pragma unroll
        for (int ch = 0; ch < 8; ++ch) {
            float4 x0 = *(const float4*)(qrow + ch * 16);
            float4 x1 = *(const float4*)(qrow + ch * 16 + 4);
            float xs[8] = {x0.x, x0.y, x0.z, x0.w, x1.x, x1.y, x1.z, x1.w};
            short8v h, l;
            #pragma unroll
            for (int j = 0; j < 8; ++j) {
                unsigned short hb = f2bf(xs[j]);
                h[j] = (short)hb;
                l[j] = (short)f2bf(xs[j] - bf2f(hb));
            }
            ah[ch] = h; al[ch] = l;
        }
    }

    f32x16 mx;
    #pragma unroll
    for (int r = 0; r < 16; ++r) mx[r] = NEGINF;

    const int srow = tid >> 3;
    const int soct = tid & 7;
    const int skey = (srow & 15) << 3;

    for (int it = 0; it < NSPAN / BN; ++it) {
        const int n0 = ks * NSPAN + it * BN;
        __syncthreads();
        {
            const float* ksrc = kp + ((size_t)(batch * SEQ + n0 + srow)) * DIM + soct * 16;
            #pragma unroll
            for (int i = 0; i < 4; ++i) {
                float4 x = *(const float4*)(ksrc + i * 4);
                int dq  = soct * 16 + i * 4;
                int idx = srow * DIM + (dq ^ skey);
                float xs[4] = {x.x, x.y, x.z, x.w};
                short4v h, l;
                #pragma unroll
                for (int j = 0; j < 4; ++j) {
                    unsigned short hb = f2bf(xs[j]);
                    h[j] = (short)hb;
                    l[j] = (short)f2bf(xs[j] - bf2f(hb));
                }
                *(short4v*)(&khi[idx]) = h;
                *(short4v*)(&klo[idx]) = l;
            }
        }
        __syncthreads();

        #pragma unroll
        for (int ns = 0; ns < 2; ++ns) {
            const int brow = ns * 32 + l31;
            const int bkey = (brow & 15) << 3;
            f32x16 c;
            #pragma unroll
            for (int r = 0; r < 16; ++r) c[r] = 0.f;
            #pragma unroll
            for (int ch = 0; ch < 8; ++ch) {
                const int d0  = ch * 16 + lhalf * 8;
                const int idx = brow * DIM + (d0 ^ bkey);
                short8v bh = *(const short8v*)(&khi[idx]);
                short8v bl = *(const short8v*)(&klo[idx]);
                c = __builtin_amdgcn_mfma_f32_32x32x16_bf16(ah[ch], bh, c, 0, 0, 0);
                c = __builtin_amdgcn_mfma_f32_32x32x16_bf16(al[ch], bh, c, 0, 0, 0);
                c = __builtin_amdgcn_mfma_f32_32x32x16_bf16(ah[ch], bl, c, 0, 0, 0);
            }
            #pragma unroll
            for (int r = 0; r < 16; ++r) mx[r] = fmaxf(mx[r], c[r]);
        }
    }

    #pragma unroll
    for (int r = 0; r < 16; ++r) {
        float v = mx[r];
        #pragma unroll
        for (int off = 16; off; off >>= 1)
            v = fmaxf(v, __shfl_xor(v, off, 64));
        mx[r] = v;
    }
    if (l31 == 0) {
        #pragma unroll
        for (int r = 0; r < 16; ++r) {
            int rr = (r & 3) + 8 * (r >> 2) + 4 * lhalf;
            mpart[((size_t)(batch * SEQ + qrow0 + rr)) * KSPLIT + ks] = mx[r] * TEMP_INV;
        }
    }
}

__global__ void reduce4_kernel(const float* __restrict__ mpart, float* __restrict__ mq)
{
    int i = blockIdx.x * 256 + threadIdx.x;
    float4 mp = *(const float4*)(mpart + (size_t)i * 4);
    mq[i] = fmaxf(fmaxf(mp.x, mp.y), fmaxf(mp.z, mp.w));
}

// ---------------------------------------------------------------------------
// Phase 2: softmax over q + top-16 threshold + renorm (reads exact mq).
// top-16(attn) == top-16(m) by monotonicity. 4 block barriers total.
// ---------------------------------------------------------------------------
__global__ __launch_bounds__(1024) void softmax_topk2_kernel(
    const float* __restrict__ mq, float* __restrict__ attn_out,
    float* __restrict__ loss_out)
{
    const int b    = blockIdx.x;
    const int tid  = threadIdx.x;
    const int wv   = tid >> 6;
    const int lane = tid & 63;
    __shared__ float cand[256];
    __shared__ float smZ[16], smW[16];
    __shared__ float bc[2];

    float m[4];
    #pragma unroll
    for (int j = 0; j < 4; ++j) m[j] = mq[b * SEQ + tid + j * 1024];

    // per-wave top-16 of its 256 values (multiset semantics: remove 1/pass)
    {
        float a0 = m[0], a1 = m[1], a2 = m[2], a3 = m[3];
        for (int pass = 0; pass < 16; ++pass) {
            float v = fmaxf(fmaxf(a0, a1), fmaxf(a2, a3));
            #pragma unroll
            for (int off = 32; off; off >>= 1) v = fmaxf(v, __shfl_xor(v, off, 64));
            bool has = (a0 == v) || (a1 == v) || (a2 == v) || (a3 == v);
            unsigned long long msk = __ballot(has);
            int leader = __ffsll(msk) - 1;
            if (lane == leader) {
                if (a0 == v) a0 = NEGINF;
                else if (a1 == v) a1 = NEGINF;
                else if (a2 == v) a2 = NEGINF;
                else a3 = NEGINF;
            }
            if (lane == pass) cand[wv * 16 + pass] = v;
        }
    }
    __syncthreads();

    // wave 0 merges 16x16 candidates -> m_max (pass 0) and m16 (pass 15)
    if (wv == 0) {
        float a0 = cand[lane * 4 + 0], a1 = cand[lane * 4 + 1];
        float a2 = cand[lane * 4 + 2], a3 = cand[lane * 4 + 3];
        float first = 0.f, last = 0.f;
        for (int pass = 0; pass < 16; ++pass) {
            float v = fmaxf(fmaxf(a0, a1), fmaxf(a2, a3));
            #pragma unroll
            for (int off = 32; off; off >>= 1) v = fmaxf(v, __shfl_xor(v, off, 64));
            bool has = (a0 == v) || (a1 == v) || (a2 == v) || (a3 == v);
            unsigned long long msk = __ballot(has);
            int leader = __ffsll(msk) - 1;
            if (lane == leader) {
                if (a0 == v) a0 = NEGINF;
                else if (a1 == v) a1 = NEGINF;
                else if (a2 == v) a2 = NEGINF;
                else a3 = NEGINF;
            }
            if (pass == 0) first = v;
            last = v;
        }
        if (lane == 0) { bc[0] = first; bc[1] = last; }
    }
    __syncthreads();

    const float S   = expf(bc[0]);   // max over q of s = exp(m)
    const float m16 = bc[1];

    float e[4]; float ls = 0.f;
    #pragma unroll
    for (int j = 0; j < 4; ++j) { e[j] = expf(expf(m[j]) - S); ls += e[j]; }
    #pragma unroll
    for (int off = 32; off; off >>= 1) ls += __shfl_xor(ls, off, 64);
    if (lane == 0) smZ[wv] = ls;
    __syncthreads();
    float Z = 0.f;
    #pragma unroll
    for (int i = 0; i < 16; ++i) Z += smZ[i];

    const float a16   = expf(expf(m16) - S) / Z;  // identical ops as owner's attn
    const float delta = a16 + EPSF;

    float w0[4]; float lw = 0.f;
    #pragma unroll
    for (int j = 0; j < 4; ++j) { w0[j] = fmaxf(e[j] / Z - delta, 0.f); lw += w0[j]; }
    #pragma unroll
    for (int off = 32; off; off >>= 1) lw += __shfl_xor(lw, off, 64);
    if (lane == 0) smW[wv] = lw;
    __syncthreads();
    float W = 0.f;
    #pragma unroll
    for (int i = 0; i < 16; ++i) W += smW[i];
    const float rW = 1.f / (W + EPSF);

    #pragma unroll
    for (int j = 0; j < 4; ++j)
        attn_out[b * SEQ + tid + j * 1024] = w0[j] * rW;
    if (b == 0 && tid == 0) loss_out[0] = 0.f;
}

// ---------------------------------------------------------------------------
// Phase 3: out[b,q,d] = sp[b,q] * v[b,0,d]
// ---------------------------------------------------------------------------
__global__ void broadcast_out_kernel(const float* __restrict__ sp,
                                     const float* __restrict__ vp,
                                     float* __restrict__ outp)
{
    int gid = blockIdx.x * 256 + threadIdx.x;
    int row = gid >> 5;
    int c4  = gid & 31;
    float  s  = sp[row];
    float4 vv = *(const float4*)(vp + (row >> 12) * DIM + c4 * 4);
    float4 o; o.x = s * vv.x; o.y = s * vv.y; o.z = s * vv.z; o.w = s * vv.w;
    *(float4*)(outp + (size_t)gid * 4) = o;
}

// ---------------------------------------------------------------------------
extern "C" void kernel_launch(void* const* d_in, const int* in_sizes, int n_in,
                              void* d_out, int out_size, void* d_ws, size_t ws_size,
                              hipStream_t stream)
{
    (void)in_sizes; (void)n_in; (void)out_size;
    const float* q = (const float*)d_in[0];
    const float* k = (const float*)d_in[1];
    const float* v = (const float*)d_in[2];
    float* out  = (float*)d_out;
    float* attn = out + (size_t)NB * SEQ * DIM;
    float* loss = attn + (size_t)NB * SEQ;

    const size_t KH_BYTES   = (size_t)NB * SEQ * DIM * 2;        // 8 MB bf16-hi K
    const size_t CAND_BYTES = (size_t)NB * SEQ * KSPLIT * 4;     // 512 KB
    const size_t MQ_BYTES   = (size_t)NB * SEQ * 4;              // 128 KB

    if (ws_size >= KH_BYTES + CAND_BYTES + MQ_BYTES) {
        unsigned short* kh  = (unsigned short*)d_ws;
        unsigned int* cand  = (unsigned int*)((char*)d_ws + KH_BYTES);
        float* mq           = (float*)((char*)d_ws + KH_BYTES + CAND_BYTES);
        hipLaunchKernelGGL(split_khi_kernel, dim3(NB * SEQ * 4 / 256), dim3(256), 0, stream, k, kh);
        hipLaunchKernelGGL(max_hi_kernel, dim3(NB * (SEQ / BM) * KSPLIT), dim3(512), 0, stream,
                           q, kh, cand);
        hipLaunchKernelGGL(rescore_kernel, dim3(NB * SEQ / 4), dim3(256), 0, stream,
                           q, k, cand, mq);
        hipLaunchKernelGGL(softmax_topk2_kernel, dim3(NB), dim3(1024), 0, stream, mq, attn, loss);
    } else {
        float* mpart = (float*)d_ws;                       // 512 KB
        float* mq    = mpart + (size_t)NB * SEQ * KSPLIT;  // 128 KB
        hipLaunchKernelGGL(max_scores_kernel, dim3(NB * (SEQ / BM) * KSPLIT), dim3(512), 0, stream,
                           q, k, mpart);
        hipLaunchKernelGGL(reduce4_kernel, dim3(NB * SEQ / 256), dim3(256), 0, stream, mpart, mq);
        hipLaunchKernelGGL(softmax_topk2_kernel, dim3(NB), dim3(1024), 0, stream, mq, attn, loss);
    }
    hipLaunchKernelGGL(broadcast_out_kernel, dim3((NB * SEQ * DIM / 4) / 256), dim3(256), 0, stream,
                       attn, v, out);
}

// Round 10
// 163.338 us; speedup vs baseline: 1.2977x; 1.0180x over previous
//
#include <hip/hip_runtime.h>
#include <math.h>

typedef __attribute__((ext_vector_type(8)))  short short8v;
typedef __attribute__((ext_vector_type(4)))  short short4v;
typedef __attribute__((ext_vector_type(16))) float f32x16;

#define NB     8
#define SEQ    4096
#define DIM    128
#define KSPLIT 4
#define NSPAN  (SEQ / KSPLIT)   // 1024 k-rows per region
#define BN     64               // fallback LDS tile
#define BM     256              // fallback q-rows per block
#define BN2    128              // fast-path k-rows per LDS tile
#define BM2    512              // fast-path q-rows per block (8 waves x 64)
#define ITERS  (NSPAN / BN2)    // 8
#define TEMP_INV (1.0f / 11.313708498984761f)
#define EPSF   1e-7f
#define NEGINF -3.0e38f

__device__ __forceinline__ unsigned short f2bf(float x) {
    unsigned u = __float_as_uint(x);
    return (unsigned short)((u + 0x7FFFu + ((u >> 16) & 1u)) >> 16); // RNE
}
__device__ __forceinline__ float bf2f(unsigned short h) {
    return __uint_as_float(((unsigned)h) << 16);
}
__device__ __forceinline__ unsigned umaxu(unsigned a, unsigned b) { return a > b ? a : b; }

// async global->LDS, 16B per lane; LDS dest is wave-uniform base + lane*16
#define GL_LDS16(gsrc, ldst)                                                              \
    __builtin_amdgcn_global_load_lds((const __attribute__((address_space(1))) void*)(gsrc), \
                                     (__attribute__((address_space(3))) void*)(ldst), 16, 0, 0)

// ---------------------------------------------------------------------------
// Pre-pass: K f32 -> bf16 HI only, row = 128 ushort (256B), element d stored
// at position d ^ ((row&15)<<3)  (pre-swizzled global, m173 pattern).
// ---------------------------------------------------------------------------
__global__ __launch_bounds__(256) void split_khi_kernel(
    const float* __restrict__ kp, unsigned short* __restrict__ kh)
{
    int t    = blockIdx.x * 256 + threadIdx.x;   // 0 .. NB*SEQ*4-1
    int row  = t >> 2;
    int part = t & 3;
    const float* src = kp + (size_t)row * DIM + part * 32;
    unsigned short* dst = kh + (size_t)row * DIM;
    int key = (row & 15) << 3;
    #pragma unroll
    for (int c = 0; c < 4; ++c) {                // 4 chunks of 8 elems
        int d = part * 32 + c * 8;               // (d^key) preserves +0..7
        float4 x0 = *(const float4*)(src + c * 8);
        float4 x1 = *(const float4*)(src + c * 8 + 4);
        short8v h;
        h[0] = (short)f2bf(x0.x); h[1] = (short)f2bf(x0.y);
        h[2] = (short)f2bf(x0.z); h[3] = (short)f2bf(x0.w);
        h[4] = (short)f2bf(x1.x); h[5] = (short)f2bf(x1.y);
        h[6] = (short)f2bf(x1.z); h[7] = (short)f2bf(x1.w);
        *(short8v*)(dst + (d ^ key)) = h;
    }
}

// ---------------------------------------------------------------------------
// Phase 1 (v3): hi-only qh.kh. 2 A-sets/wave (64 q-rows) so each B-fragment
// ds_read feeds 2 MFMAs; accumulator seeded with 128.0 (c128 trick) so scores
// exit pre-biased; pack = and_or + max_u32 with 5-bit (it,ns) field.
// Per (q-row, ks-region): top-2 candidate k for exact rescoring.
// ---------------------------------------------------------------------------
__global__ __launch_bounds__(512, 2) void max_hi2_kernel(
    const float* __restrict__ qp, const unsigned short* __restrict__ khp,
    unsigned int* __restrict__ cand)
{
    __shared__ __align__(16) unsigned short kbuf[2][BN2 * DIM]; // 2 x 32KB

    const int bid   = blockIdx.x;
    const int batch = bid & 7;          // %8 -> XCD-local batch
    const int qt    = (bid >> 3) & 7;
    const int ks    = bid >> 6;

    const int tid   = threadIdx.x;
    const int wv    = tid >> 6;
    const int lane  = tid & 63;
    const int lhalf = lane >> 5;
    const int l31   = lane & 31;
    const int qrow0 = qt * BM2 + wv * 64;

    const char* ktile0 = (const char*)(khp + ((size_t)(batch * SEQ + ks * NSPAN)) * DIM);
    const int   woff   = wv * 4096;     // per-wave byte slice of the 32KB tile

    // stage tile 0 (async; overlaps A-frag build)
    #pragma unroll
    for (int r = 0; r < 4; ++r) {
        int off = woff + r * 1024;
        GL_LDS16(ktile0 + off + lane * 16, (char*)&kbuf[0][0] + off);
    }

    // ---- A fragments: 2 sets x 8 chunks, hi only ----
    short8v ah[2][8];
    #pragma unroll
    for (int s = 0; s < 2; ++s) {
        const float* qrow = qp + ((size_t)(batch * SEQ + qrow0 + s * 32 + l31)) * DIM + lhalf * 8;
        #pragma unroll
        for (int ch = 0; ch < 8; ++ch) {
            float4 x0 = *(const float4*)(qrow + ch * 16);
            float4 x1 = *(const float4*)(qrow + ch * 16 + 4);
            short8v h;
            h[0] = (short)f2bf(x0.x); h[1] = (short)f2bf(x0.y);
            h[2] = (short)f2bf(x0.z); h[3] = (short)f2bf(x0.w);
            h[4] = (short)f2bf(x1.x); h[5] = (short)f2bf(x1.y);
            h[6] = (short)f2bf(x1.z); h[7] = (short)f2bf(x1.w);
            ah[s][ch] = h;
        }
    }

    f32x16 c128;                        // persistent C-in seed: dot + 128 for free
    #pragma unroll
    for (int r = 0; r < 16; ++r) c128[r] = 128.f;

    unsigned pk0[16], pk1[16];          // packed (value | it*4+ns) per acc-reg
    #pragma unroll
    for (int r = 0; r < 16; ++r) { pk0[r] = 0u; pk1[r] = 0u; }

    __syncthreads();   // tile 0 resident

    int cur = 0;
    for (int it = 0; it < ITERS; ++it) {
        if (it < ITERS - 1) {            // prefetch next tile (L2-hit, cheap)
            const char* src = ktile0 + (size_t)(it + 1) * (BN2 * 256);
            #pragma unroll
            for (int r = 0; r < 4; ++r) {
                int off = woff + r * 1024;
                GL_LDS16(src + off + lane * 16, (char*)&kbuf[cur ^ 1][0] + off);
            }
        }
        __builtin_amdgcn_s_setprio(1);
        const unsigned itf = (unsigned)(it << 2);
        #pragma unroll
        for (int ns = 0; ns < 4; ++ns) {
            const int  brow = ns * 32 + l31;
            const int  bkey = (l31 & 15) << 3;
            const char* base = (const char*)&kbuf[cur][0] + brow * 256;
            const unsigned fld = itf | (unsigned)ns;
            short8v bh0 = *(const short8v*)(base + 2 * ((lhalf * 8) ^ bkey));
            f32x16 c0 = __builtin_amdgcn_mfma_f32_32x32x16_bf16(ah[0][0], bh0, c128, 0, 0, 0);
            f32x16 c1 = __builtin_amdgcn_mfma_f32_32x32x16_bf16(ah[1][0], bh0, c128, 0, 0, 0);
            #pragma unroll
            for (int ch = 1; ch < 8; ++ch) {
                const int boff = 2 * ((ch * 16 + lhalf * 8) ^ bkey);
                short8v bh = *(const short8v*)(base + boff);
                c0 = __builtin_amdgcn_mfma_f32_32x32x16_bf16(ah[0][ch], bh, c0, 0, 0, 0);
                c1 = __builtin_amdgcn_mfma_f32_32x32x16_bf16(ah[1][ch], bh, c1, 0, 0, 0);
            }
            #pragma unroll
            for (int r = 0; r < 16; ++r) {
                pk0[r] = umaxu(pk0[r], (__float_as_uint(c0[r]) & 0xFFFFFFE0u) | fld);
                pk1[r] = umaxu(pk1[r], (__float_as_uint(c1[r]) & 0xFFFFFFE0u) | fld);
            }
        }
        __builtin_amdgcn_s_setprio(0);
        __syncthreads();
        cur ^= 1;
    }

    // epilogue: per set, per acc-reg row: top-2 over 32 lane-class winners
    #pragma unroll
    for (int s = 0; s < 2; ++s) {
        #pragma unroll
        for (int r = 0; r < 16; ++r) {
            unsigned key = (s == 0) ? pk0[r] : pk1[r];
            unsigned f   = key & 31u;
            unsigned t1  = key;
            unsigned t1i = (f >> 2) * 128u + (f & 3u) * 32u + (unsigned)l31;
            unsigned t2  = 0u, t2i = 0u;
            #pragma unroll
            for (int off = 1; off <= 16; off <<= 1) {   // within 32-lane half
                unsigned o1  = (unsigned)__shfl_xor((int)t1,  off, 64);
                unsigned o1i = (unsigned)__shfl_xor((int)t1i, off, 64);
                unsigned o2  = (unsigned)__shfl_xor((int)t2,  off, 64);
                unsigned o2i = (unsigned)__shfl_xor((int)t2i, off, 64);
                bool og = o1 > t1;
                unsigned n1  = og ? o1  : t1;
                unsigned n1i = og ? o1i : t1i;
                unsigned a2  = og ? t1  : o1;   // loser of top compare
                unsigned a2i = og ? t1i : o1i;
                unsigned b2  = og ? o2  : t2;   // winner side's 2nd
                unsigned b2i = og ? o2i : t2i;
                bool ag = a2 > b2;
                t1 = n1; t1i = n1i;
                t2 = ag ? a2 : b2; t2i = ag ? a2i : b2i;
            }
            if (l31 == 0) {
                int rr = (r & 3) + 8 * (r >> 2) + 4 * lhalf;  // verified 32x32 C/D row map
                cand[((size_t)(batch * SEQ + qrow0 + s * 32 + rr)) * KSPLIT + ks] =
                    (t1i & 0xFFFFu) | (t2i << 16);
            }
        }
    }
}

// ---------------------------------------------------------------------------
// Phase 1b: exact f32 rescore of the 8 candidates per q-row -> mq[b][q]
// One wave per q-row; 8 lane-groups of 8, one candidate each.
// ---------------------------------------------------------------------------
__global__ __launch_bounds__(256) void rescore_kernel(
    const float* __restrict__ qp, const float* __restrict__ kp,
    const unsigned int* __restrict__ cand, float* __restrict__ mq)
{
    const int row  = blockIdx.x * 4 + (threadIdx.x >> 6);   // b*SEQ + q
    const int lane = threadIdx.x & 63;
    const int b    = row >> 12;
    const int g    = lane >> 3;      // candidate group 0..7
    const int t8   = lane & 7;
    const int ks   = g >> 1;
    unsigned cc  = cand[(size_t)row * KSPLIT + ks];
    unsigned idx = (g & 1) ? (cc >> 16) : (cc & 0xFFFFu);   // 0..1023
    const float* qrow = qp + (size_t)row * DIM + t8 * 16;
    const float* krow = kp + ((size_t)(b * SEQ + ks * NSPAN + (int)idx)) * DIM + t8 * 16;
    float s = 0.f;
    #pragma unroll
    for (int i = 0; i < 4; ++i) {
        float4 a  = *(const float4*)(qrow + i * 4);
        float4 kk = *(const float4*)(krow + i * 4);
        s += a.x * kk.x + a.y * kk.y + a.z * kk.z + a.w * kk.w;
    }
    #pragma unroll
    for (int off = 1; off <= 4; off <<= 1) s += __shfl_xor(s, off, 64);      // sum within group
    #pragma unroll
    for (int off = 8; off <= 32; off <<= 1) s = fmaxf(s, __shfl_xor(s, off, 64)); // max across groups
    if (lane == 0) mq[row] = s * TEMP_INV;
}

// ---------------------------------------------------------------------------
// Fallback phase 1 (proven round-2 kernel): 3-product exact-ish max -> mpart
// ---------------------------------------------------------------------------
__global__ __launch_bounds__(512, 2) void max_scores_kernel(
    const float* __restrict__ qp, const float* __restrict__ kp,
    float* __restrict__ mpart)
{
    __shared__ short khi[BN * DIM];
    __shared__ short klo[BN * DIM];

    const int bid   = blockIdx.x;
    const int batch = bid & 7;
    const int qt    = (bid >> 3) & 15;
    const int ks    = bid >> 7;
    const int tid   = threadIdx.x;
    const int wv    = tid >> 6;
    const int lane  = tid & 63;
    const int lhalf = lane >> 5;
    const int l31   = lane & 31;
    const int qrow0 = qt * BM + wv * 32;

    short8v ah[8], al[8];
    {
        const float* qrow = qp + ((size_t)(batch * SEQ + qrow0 + l31)) * DIM + lhalf * 8;
        #pragma unroll
        for (int ch = 0; ch < 8; ++ch) {
            float4 x0 = *(const float4*)(qrow + ch * 16);
            float4 x1 = *(const float4*)(qrow + ch * 16 + 4);
            float xs[8] = {x0.x, x0.y, x0.z, x0.w, x1.x, x1.y, x1.z, x1.w};
            short8v h, l;
            #pragma unroll
            for (int j = 0; j < 8; ++j) {
                unsigned short hb = f2bf(xs[j]);
                h[j] = (short)hb;
                l[j] = (short)f2bf(xs[j] - bf2f(hb));
            }
            ah[ch] = h; al[ch] = l;
        }
    }

    f32x16 mx;
    #pragma unroll
    for (int r = 0; r < 16; ++r) mx[r] = NEGINF;

    const int srow = tid >> 3;
    const int soct = tid & 7;
    const int skey = (srow & 15) << 3;

    for (int it = 0; it < NSPAN / BN; ++it) {
        const int n0 = ks * NSPAN + it * BN;
        __syncthreads();
        {
            const float* ksrc = kp + ((size_t)(batch * SEQ + n0 + srow)) * DIM + soct * 16;
            #pragma unroll
            for (int i = 0; i < 4; ++i) {
                float4 x = *(const float4*)(ksrc + i * 4);
                int dq  = soct * 16 + i * 4;
                int idx = srow * DIM + (dq ^ skey);
                float xs[4] = {x.x, x.y, x.z, x.w};
                short4v h, l;
                #pragma unroll
                for (int j = 0; j < 4; ++j) {
                    unsigned short hb = f2bf(xs[j]);
                    h[j] = (short)hb;
                    l[j] = (short)f2bf(xs[j] - bf2f(hb));
                }
                *(short4v*)(&khi[idx]) = h;
                *(short4v*)(&klo[idx]) = l;
            }
        }
        __syncthreads();

        #pragma unroll
        for (int ns = 0; ns < 2; ++ns) {
            const int brow = ns * 32 + l31;
            const int bkey = (brow & 15) << 3;
            f32x16 c;
            #pragma unroll
            for (int r = 0; r < 16; ++r) c[r] = 0.f;
            #pragma unroll
            for (int ch = 0; ch < 8; ++ch) {
                const int d0  = ch * 16 + lhalf * 8;
                const int idx = brow * DIM + (d0 ^ bkey);
                short8v bh = *(const short8v*)(&khi[idx]);
                short8v bl = *(const short8v*)(&klo[idx]);
                c = __builtin_amdgcn_mfma_f32_32x32x16_bf16(ah[ch], bh, c, 0, 0, 0);
                c = __builtin_amdgcn_mfma_f32_32x32x16_bf16(al[ch], bh, c, 0, 0, 0);
                c = __builtin_amdgcn_mfma_f32_32x32x16_bf16(ah[ch], bl, c, 0, 0, 0);
            }
            #pragma unroll
            for (int r = 0; r < 16; ++r) mx[r] = fmaxf(mx[r], c[r]);
        }
    }

    #pragma unroll
    for (int r = 0; r < 16; ++r) {
        float v = mx[r];
        #pragma unroll
        for (int off = 16; off; off >>= 1)
            v = fmaxf(v, __shfl_xor(v, off, 64));
        mx[r] = v;
    }
    if (l31 == 0) {
        #pragma unroll
        for (int r = 0; r < 16; ++r) {
            int rr = (r & 3) + 8 * (r >> 2) + 4 * lhalf;
            mpart[((size_t)(batch * SEQ + qrow0 + rr)) * KSPLIT + ks] = mx[r] * TEMP_INV;
        }
    }
}

__global__ void reduce4_kernel(const float* __restrict__ mpart, float* __restrict__ mq)
{
    int i = blockIdx.x * 256 + threadIdx.x;
    float4 mp = *(const float4*)(mpart + (size_t)i * 4);
    mq[i] = fmaxf(fmaxf(mp.x, mp.y), fmaxf(mp.z, mp.w));
}

// ---------------------------------------------------------------------------
// Phase 2: softmax over q + top-16 threshold + renorm (reads exact mq).
// top-16(attn) == top-16(m) by monotonicity. 4 block barriers total.
// ---------------------------------------------------------------------------
__global__ __launch_bounds__(1024) void softmax_topk2_kernel(
    const float* __restrict__ mq, float* __restrict__ attn_out,
    float* __restrict__ loss_out)
{
    const int b    = blockIdx.x;
    const int tid  = threadIdx.x;
    const int wv   = tid >> 6;
    const int lane = tid & 63;
    __shared__ float cand[256];
    __shared__ float smZ[16], smW[16];
    __shared__ float bc[2];

    float m[4];
    #pragma unroll
    for (int j = 0; j < 4; ++j) m[j] = mq[b * SEQ + tid + j * 1024];

    // per-wave top-16 of its 256 values (multiset semantics: remove 1/pass)
    {
        float a0 = m[0], a1 = m[1], a2 = m[2], a3 = m[3];
        for (int pass = 0; pass < 16; ++pass) {
            float v = fmaxf(fmaxf(a0, a1), fmaxf(a2, a3));
            #pragma unroll
            for (int off = 32; off; off >>= 1) v = fmaxf(v, __shfl_xor(v, off, 64));
            bool has = (a0 == v) || (a1 == v) || (a2 == v) || (a3 == v);
            unsigned long long msk = __ballot(has);
            int leader = __ffsll(msk) - 1;
            if (lane == leader) {
                if (a0 == v) a0 = NEGINF;
                else if (a1 == v) a1 = NEGINF;
                else if (a2 == v) a2 = NEGINF;
                else a3 = NEGINF;
            }
            if (lane == pass) cand[wv * 16 + pass] = v;
        }
    }
    __syncthreads();

    // wave 0 merges 16x16 candidates -> m_max (pass 0) and m16 (pass 15)
    if (wv == 0) {
        float a0 = cand[lane * 4 + 0], a1 = cand[lane * 4 + 1];
        float a2 = cand[lane * 4 + 2], a3 = cand[lane * 4 + 3];
        float first = 0.f, last = 0.f;
        for (int pass = 0; pass < 16; ++pass) {
            float v = fmaxf(fmaxf(a0, a1), fmaxf(a2, a3));
            #pragma unroll
            for (int off = 32; off; off >>= 1) v = fmaxf(v, __shfl_xor(v, off, 64));
            bool has = (a0 == v) || (a1 == v) || (a2 == v) || (a3 == v);
            unsigned long long msk = __ballot(has);
            int leader = __ffsll(msk) - 1;
            if (lane == leader) {
                if (a0 == v) a0 = NEGINF;
                else if (a1 == v) a1 = NEGINF;
                else if (a2 == v) a2 = NEGINF;
                else a3 = NEGINF;
            }
            if (pass == 0) first = v;
            last = v;
        }
        if (lane == 0) { bc[0] = first; bc[1] = last; }
    }
    __syncthreads();

    const float S   = expf(bc[0]);   // max over q of s = exp(m)
    const float m16 = bc[1];

    float e[4]; float ls = 0.f;
    #pragma unroll
    for (int j = 0; j < 4; ++j) { e[j] = expf(expf(m[j]) - S); ls += e[j]; }
    #pragma unroll
    for (int off = 32; off; off >>= 1) ls += __shfl_xor(ls, off, 64);
    if (lane == 0) smZ[wv] = ls;
    __syncthreads();
    float Z = 0.f;
    #pragma unroll
    for (int i = 0; i < 16; ++i) Z += smZ[i];

    const float a16   = expf(expf(m16) - S) / Z;  // identical ops as owner's attn
    const float delta = a16 + EPSF;

    float w0[4]; float lw = 0.f;
    #pragma unroll
    for (int j = 0; j < 4; ++j) { w0[j] = fmaxf(e[j] / Z - delta, 0.f); lw += w0[j]; }
    #pragma unroll
    for (int off = 32; off; off >>= 1) lw += __shfl_xor(lw, off, 64);
    if (lane == 0) smW[wv] = lw;
    __syncthreads();
    float W = 0.f;
    #pragma unroll
    for (int i = 0; i < 16; ++i) W += smW[i];
    const float rW = 1.f / (W + EPSF);

    #pragma unroll
    for (int j = 0; j < 4; ++j)
        attn_out[b * SEQ + tid + j * 1024] = w0[j] * rW;
    if (b == 0 && tid == 0) loss_out[0] = 0.f;
}

// ---------------------------------------------------------------------------
// Phase 3: out[b,q,d] = sp[b,q] * v[b,0,d]
// ---------------------------------------------------------------------------
__global__ void broadcast_out_kernel(const float* __restrict__ sp,
                                     const float* __restrict__ vp,
                                     float* __restrict__ outp)
{
    int gid = blockIdx.x * 256 + threadIdx.x;
    int row = gid >> 5;
    int c4  = gid & 31;
    float  s  = sp[row];
    float4 vv = *(const float4*)(vp + (row >> 12) * DIM + c4 * 4);
    float4 o; o.x = s * vv.x; o.y = s * vv.y; o.z = s * vv.z; o.w = s * vv.w;
    *(float4*)(outp + (size_t)gid * 4) = o;
}

// ---------------------------------------------------------------------------
extern "C" void kernel_launch(void* const* d_in, const int* in_sizes, int n_in,
                              void* d_out, int out_size, void* d_ws, size_t ws_size,
                              hipStream_t stream)
{
    (void)in_sizes; (void)n_in; (void)out_size;
    const float* q = (const float*)d_in[0];
    const float* k = (const float*)d_in[1];
    const float* v = (const float*)d_in[2];
    float* out  = (float*)d_out;
    float* attn = out + (size_t)NB * SEQ * DIM;
    float* loss = attn + (size_t)NB * SEQ;

    const size_t KH_BYTES   = (size_t)NB * SEQ * DIM * 2;        // 8 MB bf16-hi K
    const size_t CAND_BYTES = (size_t)NB * SEQ * KSPLIT * 4;     // 512 KB
    const size_t MQ_BYTES   = (size_t)NB * SEQ * 4;              // 128 KB

    if (ws_size >= KH_BYTES + CAND_BYTES + MQ_BYTES) {
        unsigned short* kh  = (unsigned short*)d_ws;
        unsigned int* cand  = (unsigned int*)((char*)d_ws + KH_BYTES);
        float* mq           = (float*)((char*)d_ws + KH_BYTES + CAND_BYTES);
        hipLaunchKernelGGL(split_khi_kernel, dim3(NB * SEQ * 4 / 256), dim3(256), 0, stream, k, kh);
        hipLaunchKernelGGL(max_hi2_kernel, dim3(NB * (SEQ / BM2) * KSPLIT), dim3(512), 0, stream,
                           q, kh, cand);
        hipLaunchKernelGGL(rescore_kernel, dim3(NB * SEQ / 4), dim3(256), 0, stream,
                           q, k, cand, mq);
        hipLaunchKernelGGL(softmax_topk2_kernel, dim3(NB), dim3(1024), 0, stream, mq, attn, loss);
    } else {
        float* mpart = (float*)d_ws;                       // 512 KB
        float* mq    = mpart + (size_t)NB * SEQ * KSPLIT;  // 128 KB
        hipLaunchKernelGGL(max_scores_kernel, dim3(NB * (SEQ / BM) * KSPLIT), dim3(512), 0, stream,
                           q, k, mpart);
        hipLaunchKernelGGL(reduce4_kernel, dim3(NB * SEQ / 256), dim3(256), 0, stream, mpart, mq);
        hipLaunchKernelGGL(softmax_topk2_kernel, dim3(NB), dim3(1024), 0, stream, mq, attn, loss);
    }
    hipLaunchKernelGGL(broadcast_out_kernel, dim3((NB * SEQ * DIM / 4) / 256), dim3(256), 0, stream,
                       attn, v, out);
}